// Round 15
// baseline (235.311 us; speedup 1.0000x reference)
//
#include <hip/hip_runtime.h>
#include <cstdint>
#include <cstddef>
#include <cmath>

typedef float f32x4 __attribute__((ext_vector_type(4)));
typedef short bf16x8 __attribute__((ext_vector_type(8)));

#define DEVI __device__ __forceinline__

namespace {

constexpr int BB = 8, LL = 1024, CC = 1536;
constexpr int HH = 8, KDIM = 64, VDIM = 192;
constexpr int NFEAT = 192, FSZ = 32;
constexpr float SCL = 0.125f;
constexpr int MR = BB * LL;     // 8192
constexpr int NQK = HH * KDIM;  // 512
constexpr int NVD = HH * VDIM;  // 1536
constexpr int NQKV = 2 * NQK + NVD;  // 2560 stacked projection cols

DEVI short f2bf(float f) {
  unsigned u = __float_as_uint(f);
  u = (u + 0x7FFFu + ((u >> 16) & 1u)) >> 16;
  return (short)u;
}

DEVI float bf2f(short s) {
  return __uint_as_float(((unsigned)(unsigned short)s) << 16);
}

DEVI void gload_lds16(const void* g, void* l) {
  __builtin_amdgcn_global_load_lds(
      (const __attribute__((address_space(1))) void*)g,
      (__attribute__((address_space(3))) void*)l, 16, 0, 0);
}

// ---------------- convert f32 -> bf16 ----------------
__global__ void k_f32_to_bf16(const float* __restrict__ src, short* __restrict__ dst, int n) {
  int i0 = (blockIdx.x * blockDim.x + threadIdx.x) * 4;
  int stride = gridDim.x * blockDim.x * 4;
  for (int i = i0; i < n; i += stride) {
    float4 v = *reinterpret_cast<const float4*>(src + i);
    short4 o = { f2bf(v.x), f2bf(v.y), f2bf(v.z), f2bf(v.w) };
    *reinterpret_cast<short4*>(dst + i) = o;
  }
}

// ---------------- batched transpose f32 [R][Cd] -> bf16 [Cd][R] (4 weights, 1 launch) ----------------
__global__ void k_transpose_all(const float* __restrict__ s0, short* __restrict__ d0,
                                const float* __restrict__ s1, short* __restrict__ d1,
                                const float* __restrict__ s2, short* __restrict__ d2,
                                const float* __restrict__ s3, short* __restrict__ d3) {
  __shared__ float tile[32][33];
  int idx = blockIdx.x;
  const float* src; short* dst; int R, Cd, gx, local;
  if (idx < 768)       { src = s0; dst = d0; R = CC;  Cd = NQK; gx = 16; local = idx; }
  else if (idx < 1536) { src = s1; dst = d1; R = CC;  Cd = NQK; gx = 16; local = idx - 768; }
  else if (idx < 3840) { src = s2; dst = d2; R = CC;  Cd = NVD; gx = 48; local = idx - 1536; }
  else                 { src = s3; dst = d3; R = NVD; Cd = CC;  gx = 48; local = idx - 3840; }
  int c0 = (local % gx) * 32, r0 = (local / gx) * 32;
  int tx = threadIdx.x, ty = threadIdx.y;   // (32, 8)
  #pragma unroll
  for (int i = 0; i < 4; i++)
    tile[ty + i * 8][tx] = src[(size_t)(r0 + ty + i * 8) * Cd + c0 + tx];
  __syncthreads();
  #pragma unroll
  for (int i = 0; i < 4; i++)
    dst[(size_t)(c0 + ty + i * 8) * R + r0 + tx] = f2bf(tile[tx][ty + i * 8]);
}

// ---------------- build RB: row 0 = zeros, row j+1 = (basis[j] @ WR) ----------------
__global__ void k_build_r(const float* __restrict__ WR, float pmax,
                          short* __restrict__ rbuf) {
  __shared__ float feats[NFEAT];
  int jp = blockIdx.x;       // 0..2047
  int tid = threadIdx.x;     // 256
  if (jp == 0) {
    if (tid < KDIM) rbuf[tid] = 0;
    return;
  }
  int j = jp - 1;            // 0..2046
  int pos = j - (LL - 1);
  int api = pos < 0 ? -pos : pos;
  double ap = (double)api;
  float sgn = pos > 0 ? 1.0f : (pos < 0 ? -1.0f : 0.0f);
  if (tid < FSZ) {
    double xhl = 3.0 + 7.0 * (double)tid / 31.0;
    double hl = exp2(xhl);
    float fe = (float)exp2(-ap / hl);
    feats[tid] = fe; feats[FSZ + tid] = sgn * fe;
  } else if (tid < 2 * FSZ) {
    int i = tid - FSZ;
    double cw = exp2((double)(i + 1)) - 1.0;
    float fc = cw > ap ? 1.0f : 0.0f;
    feats[2 * FSZ + i] = fc; feats[3 * FSZ + i] = sgn * fc;
  } else if (tid < 3 * FSZ) {
    int i = tid - 2 * FSZ;
    double mean = 32.0 + 32.0 * (double)i;
    double conc = (mean * (1.0 / 16.0)) * (mean * (1.0 / 16.0));
    double rate = mean * (1.0 / 256.0);
    double lp = (conc - 1.0) * log(ap) - rate * ap - lgamma(conc) + conc * log(rate);
    double pdf = exp(lp) + 1e-8;
    float fg = (float)(pdf / (double)pmax);
    feats[4 * FSZ + i] = fg; feats[5 * FSZ + i] = sgn * fg;
  }
  __syncthreads();
  if (tid < KDIM) {
    float acc = 0.f;
    #pragma unroll 4
    for (int f = 0; f < NFEAT; f++) acc += feats[f] * WR[f * KDIM + tid];
    rbuf[jp * KDIM + tid] = f2bf(acc);
  }
}

// ---------------- 128x256 GEMM, BK=32, 3-buffer ring, counted vmcnt ----------------
// R15: N-tile doubled to 256 (VGPR headroom: R14 used 68 of 170). 4 waves,
// wave tile 64x128 (acc 4x8 f32x4 = 128 VGPR; 2 blocks/CU at 72KB LDS).
// Per k-step: 12 ds_read_b128 -> 32 MFMA (2x work per barrier/vmcnt stall vs
// R11's 16; reads/MFMA 0.75 vs 1.0). Same 3-ring counted-vmcnt schedule
// (6 staging loads/wave/step -> vmcnt(6)) and proven 64B-row chunk swizzle.
// MODE 0: fused QKV (region boundaries land on 256-tile edges: nt0-1=Q,
// nt2-3=K, nt4-9=V with LDS-transposed coalesced VT stores).
// MODE 1: f32 out + bias (output projection).
template<int MODE>
__global__ __launch_bounds__(256, 2)
void k_gemm3(const short* __restrict__ A, const short* __restrict__ Bt,
             int Ndim, int Kdim,
             const float* __restrict__ c0, const float* __restrict__ c1,
             const float* __restrict__ c2, const float* __restrict__ c3,
             void* __restrict__ D0, void* __restrict__ D1,
             void* __restrict__ D2, void* __restrict__ D3) {
  __shared__ short lds[36864];   // 72KB: A ring 3x128x32 @0, B ring 3x256x32 @12288

  int bid = blockIdx.x;
  int xcd = bid & 7;
  int s = bid >> 3;
  int mt = xcd * 8 + (s & 7);     // XCD-private M-stripe (L2-resident A)
  int nt = s >> 3;
  int m0 = mt * 128, n0 = nt * 256;
  int tid = threadIdx.x;
  int w = tid >> 6, l = tid & 63;
  int hi = l >> 4, lc = l & 15;
  int wr = (w >> 1) * 64, wc = (w & 1) * 128;

  // staging: lane l covers row base+(l>>2), chunk l&3 (16B units);
  // source chunk pre-swizzled by (row>>1)&3 == (l>>3)&3 (bases are x16).
  int rowoff = l >> 2;
  int schunk = ((l & 3) ^ ((l >> 3) & 3)) * 8;
  const short* gA = A + (size_t)(m0 + rowoff) * Kdim + schunk;
  const short* gB = Bt + (size_t)(n0 + rowoff) * Kdim + schunk;

  f32x4 acc[4][8] = {};
  int T = Kdim >> 5;

  auto sAp = [&](int d, int r) -> short* { return &lds[d * 4096 + r * 32]; };
  auto sBp = [&](int d, int r) -> short* { return &lds[12288 + d * 8192 + r * 32]; };

  auto stage = [&](int d, int kt) {
    #pragma unroll
    for (int j = 0; j < 2; j++) {
      int rb = j * 64 + w * 16;
      gload_lds16(gA + (size_t)rb * Kdim + kt * 32, sAp(d, rb));
    }
    #pragma unroll
    for (int j = 0; j < 4; j++) {
      int rb = j * 64 + w * 16;
      gload_lds16(gB + (size_t)rb * Kdim + kt * 32, sBp(d, rb));
    }
  };

  // prologue: tiles 0,1 in flight; wait tile 0 only (newest 6 stay out)
  stage(0, 0);
  stage(1, 1);
  asm volatile("s_waitcnt vmcnt(6)" ::: "memory");
  __builtin_amdgcn_s_barrier();
  __builtin_amdgcn_sched_barrier(0);

  int rswz = (lc >> 1) & 3;       // read-side chunk XOR
  for (int t = 0; t < T; ++t) {
    int buf = t % 3;
    bool more = (t + 2) < T;
    if (more) stage((t + 2) % 3, t + 2);

    bf16x8 af[4], bfr[8];
    #pragma unroll
    for (int ni = 0; ni < 8; ni++)
      bfr[ni] = *(const bf16x8*)&sBp(buf, wc + ni * 16 + lc)[(hi ^ rswz) * 8];
    #pragma unroll
    for (int mi = 0; mi < 4; mi++)
      af[mi] = *(const bf16x8*)&sAp(buf, wr + mi * 16 + lc)[(hi ^ rswz) * 8];
    __builtin_amdgcn_s_setprio(1);
    #pragma unroll
    for (int mi = 0; mi < 4; mi++)
      #pragma unroll
      for (int ni = 0; ni < 8; ni++)
        acc[mi][ni] = __builtin_amdgcn_mfma_f32_16x16x32_bf16(af[mi], bfr[ni], acc[mi][ni], 0, 0, 0);
    __builtin_amdgcn_s_setprio(0);

    if (more) asm volatile("s_waitcnt vmcnt(6)" ::: "memory");
    else      asm volatile("s_waitcnt vmcnt(0)" ::: "memory");
    __builtin_amdgcn_s_barrier();
    __builtin_amdgcn_sched_barrier(0);
  }
  // final barrier passed: all fragment reads done -> lds reusable as scratch.

  if (MODE == 0) {
    if (n0 < NQK) {
      // ---- Q tiles (nt 0,1): QP = (v + bq + u)*SCL ----
      #pragma unroll
      for (int ni = 0; ni < 8; ni++) {
        int col = n0 + wc + ni * 16 + lc;
        float bb = c0[col] + c3[col];
        #pragma unroll
        for (int mi = 0; mi < 4; mi++)
          #pragma unroll
          for (int rr = 0; rr < 4; rr++) {
            int row = m0 + wr + mi * 16 + hi * 4 + rr;
            ((short*)D0)[(size_t)row * NQK + col] = f2bf((acc[mi][ni][rr] + bb) * SCL);
          }
      }
    } else if (n0 < 2 * NQK) {
      // ---- K tiles (nt 2,3) ----
      #pragma unroll
      for (int ni = 0; ni < 8; ni++) {
        int c = n0 - NQK + wc + ni * 16 + lc;
        float bb = c1[c];
        #pragma unroll
        for (int mi = 0; mi < 4; mi++)
          #pragma unroll
          for (int rr = 0; rr < 4; rr++) {
            int row = m0 + wr + mi * 16 + hi * 4 + rr;
            ((short*)D2)[(size_t)row * NQK + c] = f2bf(acc[mi][ni][rr] + bb);
          }
      }
    } else {
      // ---- V tiles (nt 4..9): LDS transpose -> coalesced VT[bh][v][s] ----
      int c_base = n0 - 2 * NQK;
      short* scr = &lds[w * 8448];   // wave-private 64 x 132
      #pragma unroll
      for (int ni = 0; ni < 8; ni++) {
        float bb = c2[c_base + wc + ni * 16 + lc];
        #pragma unroll
        for (int mi = 0; mi < 4; mi++)
          #pragma unroll
          for (int rr = 0; rr < 4; rr++)
            scr[(mi * 16 + hi * 4 + rr) * 132 + ni * 16 + lc] =
                f2bf(acc[mi][ni][rr] + bb);
      }
      int bI = m0 >> 10;
      int sgbase = (m0 & (LL - 1)) + wr;
      int s_l = (l & 7) * 8;
      #pragma unroll
      for (int j = 0; j < 16; j++) {
        int col_l = j * 8 + (l >> 3);
        int c = c_base + wc + col_l;
        int hh = c / VDIM, vv = c - hh * VDIM;
        bf16x8 v8;
        #pragma unroll
        for (int e = 0; e < 8; e++) v8[e] = scr[(s_l + e) * 132 + col_l];
        short* dst = (short*)D3 + ((size_t)(bI * 8 + hh) * VDIM + vv) * LL + sgbase + s_l;
        *(bf16x8*)dst = v8;
      }
    }
  } else {
    #pragma unroll
    for (int ni = 0; ni < 8; ni++) {
      int col = n0 + wc + ni * 16 + lc;
      float bb = c0[col];
      #pragma unroll
      for (int mi = 0; mi < 4; mi++)
        #pragma unroll
        for (int rr = 0; rr < 4; rr++) {
          int row = m0 + wr + mi * 16 + hi * 4 + rr;
          ((float*)D0)[(size_t)row * Ndim + col] = acc[mi][ni][rr] + bb;
        }
    }
  }
}

// ---------------- flash attention: 128q/block, gload_lds dbuf, 1 barrier/tile ----------------
// (R14-validated; unchanged)
__global__ __launch_bounds__(256, 2)
void k_attn(const short* __restrict__ Qp, const float* __restrict__ uu,
            const short* __restrict__ Kb, const short* __restrict__ Vt,
            const short* __restrict__ Rb, short* __restrict__ AO) {
  __shared__ short sK[2][64][64];
  __shared__ short sV[2][192][64];
  __shared__ short sP[128][64];

  int bid = blockIdx.x;
  int swz = (bid & 7) * 64 + (bid >> 3);   // XCD-contiguous bh
  int qt = swz & 7, bh = swz >> 3;
  int b = bh >> 3, h = bh & 7;
  int q0 = qt * 128;
  int tid = threadIdx.x;
  int w = tid >> 6, l = tid & 63;
  int hi = l >> 4, lc = l & 15;

  int base = (w & 1) * 64;
  int par = w >> 1;
  int rbase = par ? 0 : 1024;

  bf16x8 aq1[2][2], aq2[2][2];
  {
    float u8[2][8];
    #pragma unroll
    for (int kk = 0; kk < 2; kk++)
      #pragma unroll
      for (int j = 0; j < 8; j++)
        u8[kk][j] = uu[h * KDIM + kk * 32 + hi * 8 + j] * SCL;
    #pragma unroll
    for (int mi = 0; mi < 2; mi++) {
      int qglob = q0 + base + par + 2 * (mi * 16 + lc);
      const short* qpg = Qp + (size_t)(b * LL + qglob) * NQK + h * KDIM;
      aq1[mi][0] = *(const bf16x8*)&qpg[hi * 8];
      aq1[mi][1] = *(const bf16x8*)&qpg[32 + hi * 8];
      int qsrow = q0 / 2 + base / 2 + par + mi * 16 + lc;
      const short* qsg = Qp + (size_t)(b * LL + qsrow) * NQK + h * KDIM;
      #pragma unroll
      for (int kk = 0; kk < 2; kk++) {
        bf16x8 t = *(const bf16x8*)&qsg[kk * 32 + hi * 8];
        #pragma unroll
        for (int j = 0; j < 8; j++)
          aq2[mi][kk][j] = f2bf(bf2f(t[j]) - u8[kk][j]);
      }
    }
  }

  const short* kg = Kb + (size_t)(b * LL) * NQK + h * KDIM;
  const short* vg = Vt + (size_t)bh * VDIM * LL;
  const short* rg = Rb + (size_t)rbase * KDIM;

  int srow = l >> 3;
  int schunk = ((l & 7) ^ srow) * 8;

  float mrun[2][4], lrun[2][4];
  #pragma unroll
  for (int mi = 0; mi < 2; mi++)
    #pragma unroll
    for (int r = 0; r < 4; r++) { mrun[mi][r] = -INFINITY; lrun[mi][r] = 0.f; }
  f32x4 oacc[2][12] = {};

  #pragma unroll
  for (int j = 0; j < 2; j++) {
    int rb2 = (j * 4 + w) * 8;
    gload_lds16(kg + (size_t)(rb2 + srow) * NQK + schunk, &sK[0][rb2][0]);
  }
  #pragma unroll
  for (int j = 0; j < 6; j++) {
    int rb2 = (j * 4 + w) * 8;
    gload_lds16(vg + (size_t)(rb2 + srow) * LL + schunk, &sV[0][rb2][0]);
  }
  __syncthreads();

  int swzk = (lc & 7) << 3;

  for (int t = 0; t < 16; t++) {
    int k0 = t * 64;
    int bf = t & 1;

    // RB frags first (minimal wait in the per-wave vmcnt queue)
    bf16x8 br[2][4];
    #pragma unroll
    for (int kk = 0; kk < 2; kk++)
      #pragma unroll
      for (int ni = 0; ni < 4; ni++)
        br[kk][ni] = *(const bf16x8*)&rg[(size_t)(k0 + ni * 16 + lc) * KDIM + kk * 32 + hi * 8];

    if (t < 15) {
      int kn = k0 + 64;
      #pragma unroll
      for (int j = 0; j < 2; j++) {
        int rb2 = (j * 4 + w) * 8;
        gload_lds16(kg + (size_t)(kn + rb2 + srow) * NQK + schunk, &sK[bf ^ 1][rb2][0]);
      }
      #pragma unroll
      for (int j = 0; j < 6; j++) {
        int rb2 = (j * 4 + w) * 8;
        gload_lds16(vg + (size_t)(rb2 + srow) * LL + kn + schunk, &sV[bf ^ 1][rb2][0]);
      }
    }

    f32x4 s[2][4] = {};
    #pragma unroll
    for (int kk = 0; kk < 2; kk++) {
      #pragma unroll
      for (int ni = 0; ni < 4; ni++) {
        bf16x8 bk = *(const bf16x8*)&sK[bf][ni * 16 + lc][(kk * 32 + hi * 8) ^ swzk];
        #pragma unroll
        for (int mi = 0; mi < 2; mi++) {
          s[mi][ni] = __builtin_amdgcn_mfma_f32_16x16x32_bf16(aq1[mi][kk], bk, s[mi][ni], 0, 0, 0);
          s[mi][ni] = __builtin_amdgcn_mfma_f32_16x16x32_bf16(aq2[mi][kk], br[kk][ni], s[mi][ni], 0, 0, 0);
        }
      }
    }

    float lmx[2][4];
    float dmax = -INFINITY;
    #pragma unroll
    for (int mi = 0; mi < 2; mi++) {
      #pragma unroll
      for (int r = 0; r < 4; r++) {
        float m3 = fmaxf(fmaxf(s[mi][0][r], s[mi][1][r]), fmaxf(s[mi][2][r], s[mi][3][r]));
        lmx[mi][r] = m3;
        dmax = fmaxf(dmax, m3 - mrun[mi][r]);
      }
    }

    if (__any(dmax > 8.0f)) {
      #pragma unroll
      for (int mi = 0; mi < 2; mi++) {
        #pragma unroll
        for (int r = 0; r < 4; r++) {
          float m3 = lmx[mi][r];
          m3 = fmaxf(m3, __shfl_xor(m3, 1, 64));
          m3 = fmaxf(m3, __shfl_xor(m3, 2, 64));
          m3 = fmaxf(m3, __shfl_xor(m3, 4, 64));
          m3 = fmaxf(m3, __shfl_xor(m3, 8, 64));
          float mnew = fmaxf(mrun[mi][r], m3);
          float fc = __expf(mrun[mi][r] - mnew);
          mrun[mi][r] = mnew;
          lrun[mi][r] *= fc;
          #pragma unroll
          for (int ni = 0; ni < 12; ni++)
            oacc[mi][ni][r] *= fc;
        }
      }
    }

    #pragma unroll
    for (int mi = 0; mi < 2; mi++) {
      #pragma unroll
      for (int r = 0; r < 4; r++) {
        int prow = w * 32 + mi * 16 + 4 * hi + r;
        int pxor = ((4 * hi + r) & 7) << 3;
        float ps = 0.f;
        #pragma unroll
        for (int ni = 0; ni < 4; ni++) {
          float p = __expf(s[mi][ni][r] - mrun[mi][r]);
          ps += p;
          sP[prow][(ni * 16 + lc) ^ pxor] = f2bf(p);
        }
        lrun[mi][r] += ps;
      }
    }

    __builtin_amdgcn_s_setprio(1);
    #pragma unroll
    for (int kk = 0; kk < 2; kk++) {
      bf16x8 pa[2];
      #pragma unroll
      for (int mi = 0; mi < 2; mi++)
        pa[mi] = *(const bf16x8*)&sP[w * 32 + mi * 16 + lc][(kk * 32 + hi * 8) ^ swzk];
      #pragma unroll
      for (int ni = 0; ni < 12; ni++) {
        bf16x8 bv = *(const bf16x8*)&sV[bf][ni * 16 + lc][(kk * 32 + hi * 8) ^ swzk];
        #pragma unroll
        for (int mi = 0; mi < 2; mi++)
          oacc[mi][ni] = __builtin_amdgcn_mfma_f32_16x16x32_bf16(pa[mi], bv, oacc[mi][ni], 0, 0, 0);
      }
    }
    __builtin_amdgcn_s_setprio(0);

    __syncthreads();
  }

  // epilogue: reduce the deferred l partials (once), normalize, store
  #pragma unroll
  for (int mi = 0; mi < 2; mi++) {
    #pragma unroll
    for (int r = 0; r < 4; r++) {
      float L = lrun[mi][r];
      L += __shfl_xor(L, 1, 64);
      L += __shfl_xor(L, 2, 64);
      L += __shfl_xor(L, 4, 64);
      L += __shfl_xor(L, 8, 64);
      float iv = 1.0f / L;
      int qglob = q0 + base + par + 2 * (mi * 16 + 4 * hi + r);
      short* ao = AO + (size_t)(b * LL + qglob) * NVD + h * VDIM;
      #pragma unroll
      for (int ni = 0; ni < 12; ni++)
        ao[ni * 16 + lc] = f2bf(oacc[mi][ni][r] * iv);
    }
  }
}

}  // namespace

extern "C" void kernel_launch(void* const* d_in, const int* in_sizes, int n_in,
                              void* d_out, int out_size, void* d_ws, size_t ws_size,
                              hipStream_t stream) {
  (void)in_sizes; (void)n_in; (void)out_size; (void)ws_size;
  const float* x  = (const float*)d_in[0];
  const float* Wq = (const float*)d_in[1];
  const float* bq = (const float*)d_in[2];
  const float* Wk = (const float*)d_in[3];
  const float* bk = (const float*)d_in[4];
  const float* Wv = (const float*)d_in[5];
  const float* bv = (const float*)d_in[6];
  const float* Wo = (const float*)d_in[7];
  const float* bo = (const float*)d_in[8];
  const float* WR = (const float*)d_in[9];
  const float* uu = (const float*)d_in[10];
  // d_in[11] (v) intentionally unused: term4 is constant along the softmax axis.

  // Host-side gamma-pdf max (input-independent; unimodal -> mode neighborhood).
  double pmaxd = 0.0;
  for (int i = 0; i < 32; i++) {
    double mean = 32.0 + 32.0 * (double)i;
    double conc = (mean / 16.0) * (mean / 16.0);
    double rate = mean / 256.0;
    double mode = (conc - 1.0) / rate;
    long m0i = (long)floor(mode);
    for (long dj = -2; dj <= 2; dj++) {
      long ap = m0i + dj;
      if (ap < 1) ap = 1;
      if (ap > 1023) ap = 1023;
      double lp = (conc - 1.0) * log((double)ap) - rate * (double)ap
                  - lgamma(conc) + conc * log(rate);
      double pdf = exp(lp) + 1e-8;
      if (pdf > pmaxd) pmaxd = pdf;
    }
  }
  float pmax = (float)pmaxd;

  char* ws = (char*)d_ws;
  size_t off = 0;
  auto alloc = [&](size_t bytes) -> void* {
    void* p = ws + off;
    off += (bytes + 255) & ~(size_t)255;
    return p;
  };
  short* RB      = (short*)alloc((size_t)2048 * 64 * 2);
  short* XB      = (short*)alloc((size_t)MR * CC * 2);
  short* WALL    = (short*)alloc((size_t)NQKV * CC * 2);   // [WQT;WKT;WVT]
  short* WOT     = (short*)alloc((size_t)CC * NVD * 2);
  short* QP      = (short*)alloc((size_t)MR * NQK * 2);
  short* KB      = (short*)alloc((size_t)MR * NQK * 2);
  short* VT      = (short*)alloc((size_t)MR * NVD * 2);
  short* AO      = (short*)alloc((size_t)MR * NVD * 2);

  short* WQT = WALL;
  short* WKT = WALL + (size_t)NQK * CC;
  short* WVT = WALL + (size_t)(2 * NQK) * CC;

  k_f32_to_bf16<<<2048, 256, 0, stream>>>(x, XB, MR * CC);
  k_transpose_all<<<6144, dim3(32, 8), 0, stream>>>(Wq, WQT, Wk, WKT, Wv, WVT, Wo, WOT);
  k_build_r<<<2048, 256, 0, stream>>>(WR, pmax, RB);
  // fused Q/K/V projections: 64 M x 10 N = 640 blocks (128x256 tiles)
  k_gemm3<0><<<dim3(MR / 128 * (NQKV / 256)), 256, 0, stream>>>(
      XB, WALL, NQKV, CC, bq, bk, bv, uu, QP, nullptr, KB, VT);
  k_attn<<<dim3(LL / 128 * BB * HH), 256, 0, stream>>>(QP, uu, KB, VT, RB, AO);
  // output projection: 64 x 6 = 384 blocks
  k_gemm3<1><<<dim3(MR / 128 * (CC / 256)), 256, 0, stream>>>(
      AO, WOT, CC, NVD, bo, nullptr, nullptr, nullptr, d_out, nullptr, nullptr, nullptr);
}

// Round 16
// 233.149 us; speedup vs baseline: 1.0093x; 1.0093x over previous
//
#include <hip/hip_runtime.h>
#include <cstdint>
#include <cstddef>
#include <cmath>

typedef float f32x4 __attribute__((ext_vector_type(4)));
typedef short bf16x8 __attribute__((ext_vector_type(8)));

#define DEVI __device__ __forceinline__

namespace {

constexpr int BB = 8, LL = 1024, CC = 1536;
constexpr int HH = 8, KDIM = 64, VDIM = 192;
constexpr int NFEAT = 192, FSZ = 32;
constexpr float SCL = 0.125f;
constexpr int MR = BB * LL;     // 8192
constexpr int NQK = HH * KDIM;  // 512
constexpr int NVD = HH * VDIM;  // 1536
constexpr int NQKV = 2 * NQK + NVD;  // 2560 stacked projection cols

DEVI short f2bf(float f) {
  unsigned u = __float_as_uint(f);
  u = (u + 0x7FFFu + ((u >> 16) & 1u)) >> 16;
  return (short)u;
}

DEVI float bf2f(short s) {
  return __uint_as_float(((unsigned)(unsigned short)s) << 16);
}

DEVI void gload_lds16(const void* g, void* l) {
  __builtin_amdgcn_global_load_lds(
      (const __attribute__((address_space(1))) void*)g,
      (__attribute__((address_space(3))) void*)l, 16, 0, 0);
}

// ---------------- convert f32 -> bf16 ----------------
__global__ void k_f32_to_bf16(const float* __restrict__ src, short* __restrict__ dst, int n) {
  int i0 = (blockIdx.x * blockDim.x + threadIdx.x) * 4;
  int stride = gridDim.x * blockDim.x * 4;
  for (int i = i0; i < n; i += stride) {
    float4 v = *reinterpret_cast<const float4*>(src + i);
    short4 o = { f2bf(v.x), f2bf(v.y), f2bf(v.z), f2bf(v.w) };
    *reinterpret_cast<short4*>(dst + i) = o;
  }
}

// ---------------- batched transpose f32 [R][Cd] -> bf16 [Cd][R] (4 weights, 1 launch) ----------------
__global__ void k_transpose_all(const float* __restrict__ s0, short* __restrict__ d0,
                                const float* __restrict__ s1, short* __restrict__ d1,
                                const float* __restrict__ s2, short* __restrict__ d2,
                                const float* __restrict__ s3, short* __restrict__ d3) {
  __shared__ float tile[32][33];
  int idx = blockIdx.x;
  const float* src; short* dst; int R, Cd, gx, local;
  if (idx < 768)       { src = s0; dst = d0; R = CC;  Cd = NQK; gx = 16; local = idx; }
  else if (idx < 1536) { src = s1; dst = d1; R = CC;  Cd = NQK; gx = 16; local = idx - 768; }
  else if (idx < 3840) { src = s2; dst = d2; R = CC;  Cd = NVD; gx = 48; local = idx - 1536; }
  else                 { src = s3; dst = d3; R = NVD; Cd = CC;  gx = 48; local = idx - 3840; }
  int c0 = (local % gx) * 32, r0 = (local / gx) * 32;
  int tx = threadIdx.x, ty = threadIdx.y;   // (32, 8)
  #pragma unroll
  for (int i = 0; i < 4; i++)
    tile[ty + i * 8][tx] = src[(size_t)(r0 + ty + i * 8) * Cd + c0 + tx];
  __syncthreads();
  #pragma unroll
  for (int i = 0; i < 4; i++)
    dst[(size_t)(c0 + ty + i * 8) * R + r0 + tx] = f2bf(tile[tx][ty + i * 8]);
}

// ---------------- build RB: row 0 = zeros, row j+1 = (basis[j] @ WR) ----------------
__global__ void k_build_r(const float* __restrict__ WR, float pmax,
                          short* __restrict__ rbuf) {
  __shared__ float feats[NFEAT];
  int jp = blockIdx.x;       // 0..2047
  int tid = threadIdx.x;     // 256
  if (jp == 0) {
    if (tid < KDIM) rbuf[tid] = 0;
    return;
  }
  int j = jp - 1;            // 0..2046
  int pos = j - (LL - 1);
  int api = pos < 0 ? -pos : pos;
  double ap = (double)api;
  float sgn = pos > 0 ? 1.0f : (pos < 0 ? -1.0f : 0.0f);
  if (tid < FSZ) {
    double xhl = 3.0 + 7.0 * (double)tid / 31.0;
    double hl = exp2(xhl);
    float fe = (float)exp2(-ap / hl);
    feats[tid] = fe; feats[FSZ + tid] = sgn * fe;
  } else if (tid < 2 * FSZ) {
    int i = tid - FSZ;
    double cw = exp2((double)(i + 1)) - 1.0;
    float fc = cw > ap ? 1.0f : 0.0f;
    feats[2 * FSZ + i] = fc; feats[3 * FSZ + i] = sgn * fc;
  } else if (tid < 3 * FSZ) {
    int i = tid - 2 * FSZ;
    double mean = 32.0 + 32.0 * (double)i;
    double conc = (mean * (1.0 / 16.0)) * (mean * (1.0 / 16.0));
    double rate = mean * (1.0 / 256.0);
    double lp = (conc - 1.0) * log(ap) - rate * ap - lgamma(conc) + conc * log(rate);
    double pdf = exp(lp) + 1e-8;
    float fg = (float)(pdf / (double)pmax);
    feats[4 * FSZ + i] = fg; feats[5 * FSZ + i] = sgn * fg;
  }
  __syncthreads();
  if (tid < KDIM) {
    float acc = 0.f;
    #pragma unroll 4
    for (int f = 0; f < NFEAT; f++) acc += feats[f] * WR[f * KDIM + tid];
    rbuf[jp * KDIM + tid] = f2bf(acc);
  }
}

// ---------------- 128x128 GEMM, BK=32, 3-buffer ring, counted vmcnt ----------------
// (R14-validated configuration: the measured local optimum. R15's 128x256
// variant regressed -- occupancy 3->2 blocks/CU cost more than 2x work/stall
// bought. Epilogues: Q region writes QP only; V region LDS-transposed to
// coalesced VT stores.) MODE 0: fused QKV. MODE 1: f32 out + bias.
template<int MODE>
__global__ __launch_bounds__(256, 3)
void k_gemm3(const short* __restrict__ A, const short* __restrict__ Bt,
             int Ndim, int Kdim,
             const float* __restrict__ c0, const float* __restrict__ c1,
             const float* __restrict__ c2, const float* __restrict__ c3,
             void* __restrict__ D0, void* __restrict__ D1,
             void* __restrict__ D2, void* __restrict__ D3) {
  __shared__ short sAB[2][3][128][32];   // [0]=A ring, [1]=B ring (48KB)

  int bid = blockIdx.x;
  int xcd = bid & 7;
  int s = bid >> 3;
  int mt = xcd * 8 + (s & 7);
  int nt = s >> 3;
  int m0 = mt * 128, n0 = nt * 128;
  int tid = threadIdx.x;
  int w = tid >> 6, l = tid & 63;
  int hi = l >> 4, lc = l & 15;
  int wr = (w >> 1) * 64, wc = (w & 1) * 64;

  int rowoff = l >> 2;
  int schunk = ((l & 3) ^ ((l >> 3) & 3)) * 8;
  const short* gA = A + (size_t)(m0 + rowoff) * Kdim + schunk;
  const short* gB = Bt + (size_t)(n0 + rowoff) * Kdim + schunk;

  f32x4 acc[4][4] = {};
  int T = Kdim >> 5;

  auto stage = [&](int d, int kt) {
    #pragma unroll
    for (int j = 0; j < 2; j++) {
      int rb = j * 64 + w * 16;
      gload_lds16(gA + (size_t)rb * Kdim + kt * 32, &sAB[0][d][rb][0]);
      gload_lds16(gB + (size_t)rb * Kdim + kt * 32, &sAB[1][d][rb][0]);
    }
  };

  stage(0, 0);
  stage(1, 1);
  asm volatile("s_waitcnt vmcnt(4)" ::: "memory");
  __builtin_amdgcn_s_barrier();
  __builtin_amdgcn_sched_barrier(0);

  int rswz = (lc >> 1) & 3;
  for (int t = 0; t < T; ++t) {
    int buf = t % 3;
    bool more = (t + 2) < T;
    if (more) stage((t + 2) % 3, t + 2);

    bf16x8 af[4], bfr[4];
    #pragma unroll
    for (int ni = 0; ni < 4; ni++)
      bfr[ni] = *(const bf16x8*)&sAB[1][buf][wc + ni * 16 + lc][(hi ^ rswz) * 8];
    #pragma unroll
    for (int mi = 0; mi < 4; mi++)
      af[mi] = *(const bf16x8*)&sAB[0][buf][wr + mi * 16 + lc][(hi ^ rswz) * 8];
    __builtin_amdgcn_s_setprio(1);
    #pragma unroll
    for (int mi = 0; mi < 4; mi++)
      #pragma unroll
      for (int ni = 0; ni < 4; ni++)
        acc[mi][ni] = __builtin_amdgcn_mfma_f32_16x16x32_bf16(af[mi], bfr[ni], acc[mi][ni], 0, 0, 0);
    __builtin_amdgcn_s_setprio(0);

    if (more) asm volatile("s_waitcnt vmcnt(4)" ::: "memory");
    else      asm volatile("s_waitcnt vmcnt(0)" ::: "memory");
    __builtin_amdgcn_s_barrier();
    __builtin_amdgcn_sched_barrier(0);
  }
  // after the final barrier all waves' LDS fragment reads are complete.

  if (MODE == 0) {
    if (n0 < NQK) {
      // ---- Q region: write QP = (v + bq + u)*SCL only ----
      #pragma unroll
      for (int ni = 0; ni < 4; ni++) {
        int col = n0 + wc + ni * 16 + lc;
        float bb = c0[col] + c3[col];
        #pragma unroll
        for (int mi = 0; mi < 4; mi++)
          #pragma unroll
          for (int rr = 0; rr < 4; rr++) {
            int row = m0 + wr + mi * 16 + hi * 4 + rr;
            ((short*)D0)[(size_t)row * NQK + col] = f2bf((acc[mi][ni][rr] + bb) * SCL);
          }
      }
    } else if (n0 < 2 * NQK) {
      // ---- K region ----
      #pragma unroll
      for (int ni = 0; ni < 4; ni++) {
        int c = n0 - NQK + wc + ni * 16 + lc;
        float bb = c1[c];
        #pragma unroll
        for (int mi = 0; mi < 4; mi++)
          #pragma unroll
          for (int rr = 0; rr < 4; rr++) {
            int row = m0 + wr + mi * 16 + hi * 4 + rr;
            ((short*)D2)[(size_t)row * NQK + c] = f2bf(acc[mi][ni][rr] + bb);
          }
      }
    } else {
      // ---- V region: LDS transpose -> coalesced VT[bh][v][s] stores ----
      int c_base = n0 - 2 * NQK;
      short* scr = &sAB[0][0][0][0] + w * (64 * 68);   // wave-private 64x68
      float bbv[4];
      #pragma unroll
      for (int ni = 0; ni < 4; ni++) bbv[ni] = c2[c_base + wc + ni * 16 + lc];
      #pragma unroll
      for (int ni = 0; ni < 4; ni++)
        #pragma unroll
        for (int mi = 0; mi < 4; mi++)
          #pragma unroll
          for (int rr = 0; rr < 4; rr++)
            scr[(mi * 16 + hi * 4 + rr) * 68 + ni * 16 + lc] =
                f2bf(acc[mi][ni][rr] + bbv[ni]);
      int bI = m0 >> 10;
      int sgbase = (m0 & (LL - 1)) + wr;
      #pragma unroll
      for (int j = 0; j < 8; j++) {
        int col_l = j * 8 + (l >> 3);
        int s_l = (l & 7) * 8;
        int c = c_base + wc + col_l;
        int hh = c / VDIM, vv = c - hh * VDIM;
        bf16x8 v8;
        #pragma unroll
        for (int e = 0; e < 8; e++) v8[e] = scr[(s_l + e) * 68 + col_l];
        short* dst = (short*)D3 + ((size_t)(bI * 8 + hh) * VDIM + vv) * LL + sgbase + s_l;
        *(bf16x8*)dst = v8;
      }
    }
  } else {
    #pragma unroll
    for (int ni = 0; ni < 4; ni++) {
      int col = n0 + wc + ni * 16 + lc;
      float bb = c0[col];
      #pragma unroll
      for (int mi = 0; mi < 4; mi++)
        #pragma unroll
        for (int rr = 0; rr < 4; rr++) {
          int row = m0 + wr + mi * 16 + hi * 4 + rr;
          ((float*)D0)[(size_t)row * Ndim + col] = acc[mi][ni][rr] + bb;
        }
    }
  }
}

// ---------------- flash attention: 128q/block, gload_lds dbuf, 1 barrier/tile ----------------
// (R14-validated; unchanged)
__global__ __launch_bounds__(256, 2)
void k_attn(const short* __restrict__ Qp, const float* __restrict__ uu,
            const short* __restrict__ Kb, const short* __restrict__ Vt,
            const short* __restrict__ Rb, short* __restrict__ AO) {
  __shared__ short sK[2][64][64];
  __shared__ short sV[2][192][64];
  __shared__ short sP[128][64];

  int bid = blockIdx.x;
  int swz = (bid & 7) * 64 + (bid >> 3);   // XCD-contiguous bh
  int qt = swz & 7, bh = swz >> 3;
  int b = bh >> 3, h = bh & 7;
  int q0 = qt * 128;
  int tid = threadIdx.x;
  int w = tid >> 6, l = tid & 63;
  int hi = l >> 4, lc = l & 15;

  int base = (w & 1) * 64;
  int par = w >> 1;
  int rbase = par ? 0 : 1024;

  bf16x8 aq1[2][2], aq2[2][2];
  {
    float u8[2][8];
    #pragma unroll
    for (int kk = 0; kk < 2; kk++)
      #pragma unroll
      for (int j = 0; j < 8; j++)
        u8[kk][j] = uu[h * KDIM + kk * 32 + hi * 8 + j] * SCL;
    #pragma unroll
    for (int mi = 0; mi < 2; mi++) {
      int qglob = q0 + base + par + 2 * (mi * 16 + lc);
      const short* qpg = Qp + (size_t)(b * LL + qglob) * NQK + h * KDIM;
      aq1[mi][0] = *(const bf16x8*)&qpg[hi * 8];
      aq1[mi][1] = *(const bf16x8*)&qpg[32 + hi * 8];
      int qsrow = q0 / 2 + base / 2 + par + mi * 16 + lc;
      const short* qsg = Qp + (size_t)(b * LL + qsrow) * NQK + h * KDIM;
      #pragma unroll
      for (int kk = 0; kk < 2; kk++) {
        bf16x8 t = *(const bf16x8*)&qsg[kk * 32 + hi * 8];
        #pragma unroll
        for (int j = 0; j < 8; j++)
          aq2[mi][kk][j] = f2bf(bf2f(t[j]) - u8[kk][j]);
      }
    }
  }

  const short* kg = Kb + (size_t)(b * LL) * NQK + h * KDIM;
  const short* vg = Vt + (size_t)bh * VDIM * LL;
  const short* rg = Rb + (size_t)rbase * KDIM;

  int srow = l >> 3;
  int schunk = ((l & 7) ^ srow) * 8;

  float mrun[2][4], lrun[2][4];
  #pragma unroll
  for (int mi = 0; mi < 2; mi++)
    #pragma unroll
    for (int r = 0; r < 4; r++) { mrun[mi][r] = -INFINITY; lrun[mi][r] = 0.f; }
  f32x4 oacc[2][12] = {};

  #pragma unroll
  for (int j = 0; j < 2; j++) {
    int rb2 = (j * 4 + w) * 8;
    gload_lds16(kg + (size_t)(rb2 + srow) * NQK + schunk, &sK[0][rb2][0]);
  }
  #pragma unroll
  for (int j = 0; j < 6; j++) {
    int rb2 = (j * 4 + w) * 8;
    gload_lds16(vg + (size_t)(rb2 + srow) * LL + schunk, &sV[0][rb2][0]);
  }
  __syncthreads();

  int swzk = (lc & 7) << 3;

  for (int t = 0; t < 16; t++) {
    int k0 = t * 64;
    int bf = t & 1;

    // RB frags first (minimal wait in the per-wave vmcnt queue)
    bf16x8 br[2][4];
    #pragma unroll
    for (int kk = 0; kk < 2; kk++)
      #pragma unroll
      for (int ni = 0; ni < 4; ni++)
        br[kk][ni] = *(const bf16x8*)&rg[(size_t)(k0 + ni * 16 + lc) * KDIM + kk * 32 + hi * 8];

    if (t < 15) {
      int kn = k0 + 64;
      #pragma unroll
      for (int j = 0; j < 2; j++) {
        int rb2 = (j * 4 + w) * 8;
        gload_lds16(kg + (size_t)(kn + rb2 + srow) * NQK + schunk, &sK[bf ^ 1][rb2][0]);
      }
      #pragma unroll
      for (int j = 0; j < 6; j++) {
        int rb2 = (j * 4 + w) * 8;
        gload_lds16(vg + (size_t)(rb2 + srow) * LL + kn + schunk, &sV[bf ^ 1][rb2][0]);
      }
    }

    f32x4 s[2][4] = {};
    #pragma unroll
    for (int kk = 0; kk < 2; kk++) {
      #pragma unroll
      for (int ni = 0; ni < 4; ni++) {
        bf16x8 bk = *(const bf16x8*)&sK[bf][ni * 16 + lc][(kk * 32 + hi * 8) ^ swzk];
        #pragma unroll
        for (int mi = 0; mi < 2; mi++) {
          s[mi][ni] = __builtin_amdgcn_mfma_f32_16x16x32_bf16(aq1[mi][kk], bk, s[mi][ni], 0, 0, 0);
          s[mi][ni] = __builtin_amdgcn_mfma_f32_16x16x32_bf16(aq2[mi][kk], br[kk][ni], s[mi][ni], 0, 0, 0);
        }
      }
    }

    float lmx[2][4];
    float dmax = -INFINITY;
    #pragma unroll
    for (int mi = 0; mi < 2; mi++) {
      #pragma unroll
      for (int r = 0; r < 4; r++) {
        float m3 = fmaxf(fmaxf(s[mi][0][r], s[mi][1][r]), fmaxf(s[mi][2][r], s[mi][3][r]));
        lmx[mi][r] = m3;
        dmax = fmaxf(dmax, m3 - mrun[mi][r]);
      }
    }

    if (__any(dmax > 8.0f)) {
      #pragma unroll
      for (int mi = 0; mi < 2; mi++) {
        #pragma unroll
        for (int r = 0; r < 4; r++) {
          float m3 = lmx[mi][r];
          m3 = fmaxf(m3, __shfl_xor(m3, 1, 64));
          m3 = fmaxf(m3, __shfl_xor(m3, 2, 64));
          m3 = fmaxf(m3, __shfl_xor(m3, 4, 64));
          m3 = fmaxf(m3, __shfl_xor(m3, 8, 64));
          float mnew = fmaxf(mrun[mi][r], m3);
          float fc = __expf(mrun[mi][r] - mnew);
          mrun[mi][r] = mnew;
          lrun[mi][r] *= fc;
          #pragma unroll
          for (int ni = 0; ni < 12; ni++)
            oacc[mi][ni][r] *= fc;
        }
      }
    }

    #pragma unroll
    for (int mi = 0; mi < 2; mi++) {
      #pragma unroll
      for (int r = 0; r < 4; r++) {
        int prow = w * 32 + mi * 16 + 4 * hi + r;
        int pxor = ((4 * hi + r) & 7) << 3;
        float ps = 0.f;
        #pragma unroll
        for (int ni = 0; ni < 4; ni++) {
          float p = __expf(s[mi][ni][r] - mrun[mi][r]);
          ps += p;
          sP[prow][(ni * 16 + lc) ^ pxor] = f2bf(p);
        }
        lrun[mi][r] += ps;
      }
    }

    __builtin_amdgcn_s_setprio(1);
    #pragma unroll
    for (int kk = 0; kk < 2; kk++) {
      bf16x8 pa[2];
      #pragma unroll
      for (int mi = 0; mi < 2; mi++)
        pa[mi] = *(const bf16x8*)&sP[w * 32 + mi * 16 + lc][(kk * 32 + hi * 8) ^ swzk];
      #pragma unroll
      for (int ni = 0; ni < 12; ni++) {
        bf16x8 bv = *(const bf16x8*)&sV[bf][ni * 16 + lc][(kk * 32 + hi * 8) ^ swzk];
        #pragma unroll
        for (int mi = 0; mi < 2; mi++)
          oacc[mi][ni] = __builtin_amdgcn_mfma_f32_16x16x32_bf16(pa[mi], bv, oacc[mi][ni], 0, 0, 0);
      }
    }
    __builtin_amdgcn_s_setprio(0);

    __syncthreads();
  }

  // epilogue: reduce the deferred l partials (once), normalize, store
  #pragma unroll
  for (int mi = 0; mi < 2; mi++) {
    #pragma unroll
    for (int r = 0; r < 4; r++) {
      float L = lrun[mi][r];
      L += __shfl_xor(L, 1, 64);
      L += __shfl_xor(L, 2, 64);
      L += __shfl_xor(L, 4, 64);
      L += __shfl_xor(L, 8, 64);
      float iv = 1.0f / L;
      int qglob = q0 + base + par + 2 * (mi * 16 + 4 * hi + r);
      short* ao = AO + (size_t)(b * LL + qglob) * NVD + h * VDIM;
      #pragma unroll
      for (int ni = 0; ni < 12; ni++)
        ao[ni * 16 + lc] = f2bf(oacc[mi][ni][r] * iv);
    }
  }
}

}  // namespace

extern "C" void kernel_launch(void* const* d_in, const int* in_sizes, int n_in,
                              void* d_out, int out_size, void* d_ws, size_t ws_size,
                              hipStream_t stream) {
  (void)in_sizes; (void)n_in; (void)out_size; (void)ws_size;
  const float* x  = (const float*)d_in[0];
  const float* Wq = (const float*)d_in[1];
  const float* bq = (const float*)d_in[2];
  const float* Wk = (const float*)d_in[3];
  const float* bk = (const float*)d_in[4];
  const float* Wv = (const float*)d_in[5];
  const float* bv = (const float*)d_in[6];
  const float* Wo = (const float*)d_in[7];
  const float* bo = (const float*)d_in[8];
  const float* WR = (const float*)d_in[9];
  const float* uu = (const float*)d_in[10];
  // d_in[11] (v) intentionally unused: term4 is constant along the softmax axis.

  // Host-side gamma-pdf max (input-independent; unimodal -> mode neighborhood).
  double pmaxd = 0.0;
  for (int i = 0; i < 32; i++) {
    double mean = 32.0 + 32.0 * (double)i;
    double conc = (mean / 16.0) * (mean / 16.0);
    double rate = mean / 256.0;
    double mode = (conc - 1.0) / rate;
    long m0i = (long)floor(mode);
    for (long dj = -2; dj <= 2; dj++) {
      long ap = m0i + dj;
      if (ap < 1) ap = 1;
      if (ap > 1023) ap = 1023;
      double lp = (conc - 1.0) * log((double)ap) - rate * (double)ap
                  - lgamma(conc) + conc * log(rate);
      double pdf = exp(lp) + 1e-8;
      if (pdf > pmaxd) pmaxd = pdf;
    }
  }
  float pmax = (float)pmaxd;

  char* ws = (char*)d_ws;
  size_t off = 0;
  auto alloc = [&](size_t bytes) -> void* {
    void* p = ws + off;
    off += (bytes + 255) & ~(size_t)255;
    return p;
  };
  short* RB      = (short*)alloc((size_t)2048 * 64 * 2);
  short* XB      = (short*)alloc((size_t)MR * CC * 2);
  short* WALL    = (short*)alloc((size_t)NQKV * CC * 2);   // [WQT;WKT;WVT]
  short* WOT     = (short*)alloc((size_t)CC * NVD * 2);
  short* QP      = (short*)alloc((size_t)MR * NQK * 2);
  short* KB      = (short*)alloc((size_t)MR * NQK * 2);
  short* VT      = (short*)alloc((size_t)MR * NVD * 2);
  short* AO      = (short*)alloc((size_t)MR * NVD * 2);

  short* WQT = WALL;
  short* WKT = WALL + (size_t)NQK * CC;
  short* WVT = WALL + (size_t)(2 * NQK) * CC;

  k_f32_to_bf16<<<2048, 256, 0, stream>>>(x, XB, MR * CC);
  k_transpose_all<<<6144, dim3(32, 8), 0, stream>>>(Wq, WQT, Wk, WKT, Wv, WVT, Wo, WOT);
  k_build_r<<<2048, 256, 0, stream>>>(WR, pmax, RB);
  // fused Q/K/V projections (QP only + V transposed via LDS): 64 x 20 = 1280 blocks
  k_gemm3<0><<<dim3(MR / 128 * (NQKV / 128)), 256, 0, stream>>>(
      XB, WALL, NQKV, CC, bq, bk, bv, uu, QP, nullptr, KB, VT);
  k_attn<<<dim3(LL / 128 * BB * HH), 256, 0, stream>>>(QP, uu, KB, VT, RB, AO);
  // output projection: 64 x 12 = 768 blocks
  k_gemm3<1><<<dim3(MR / 128 * (CC / 128)), 256, 0, stream>>>(
      AO, WOT, CC, NVD, bo, nullptr, nullptr, nullptr, d_out, nullptr, nullptr, nullptr);
}

// Round 17
// 227.411 us; speedup vs baseline: 1.0347x; 1.0252x over previous
//
#include <hip/hip_runtime.h>
#include <cstdint>
#include <cstddef>
#include <cmath>

typedef float f32x4 __attribute__((ext_vector_type(4)));
typedef short bf16x8 __attribute__((ext_vector_type(8)));

#define DEVI __device__ __forceinline__

namespace {

constexpr int BB = 8, LL = 1024, CC = 1536;
constexpr int HH = 8, KDIM = 64, VDIM = 192;
constexpr int NFEAT = 192, FSZ = 32;
constexpr float SCL = 0.125f;
constexpr int MR = BB * LL;     // 8192
constexpr int NQK = HH * KDIM;  // 512
constexpr int NVD = HH * VDIM;  // 1536
constexpr int NQKV = 2 * NQK + NVD;  // 2560 stacked projection cols

DEVI short f2bf(float f) {
  unsigned u = __float_as_uint(f);
  u = (u + 0x7FFFu + ((u >> 16) & 1u)) >> 16;
  return (short)u;
}

DEVI float bf2f(short s) {
  return __uint_as_float(((unsigned)(unsigned short)s) << 16);
}

DEVI void gload_lds16(const void* g, void* l) {
  __builtin_amdgcn_global_load_lds(
      (const __attribute__((address_space(1))) void*)g,
      (__attribute__((address_space(3))) void*)l, 16, 0, 0);
}

// ---------------- fused preprocessing: convert + 4 transposes + RB build ----
// blocks [0,2048): x f32->bf16 (grid-stride); [2048,8192): weight transposes;
// [8192,10240): RB rows. Independent workloads, disjoint buffers -> safe to
// co-schedule; saves 2 launches and overlaps the small work under the
// BW-bound conversion.
__global__ void k_prep(const float* __restrict__ x, short* __restrict__ XB,
                       const float* __restrict__ Wq, short* __restrict__ WQT,
                       const float* __restrict__ Wk, short* __restrict__ WKT,
                       const float* __restrict__ Wv, short* __restrict__ WVT,
                       const float* __restrict__ Wo, short* __restrict__ WOT,
                       const float* __restrict__ WR, float pmax,
                       short* __restrict__ RB) {
  __shared__ float smem[1056];   // transpose tile 32x33 / feats[192]
  int bid = blockIdx.x;
  int tid = threadIdx.x;

  if (bid < 2048) {
    // ---- f32 -> bf16 conversion ----
    int i0 = (bid * 256 + tid) * 4;
    int stride = 2048 * 256 * 4;
    for (int i = i0; i < MR * CC; i += stride) {
      float4 v = *reinterpret_cast<const float4*>(x + i);
      short4 o = { f2bf(v.x), f2bf(v.y), f2bf(v.z), f2bf(v.w) };
      *reinterpret_cast<short4*>(XB + i) = o;
    }
  } else if (bid < 8192) {
    // ---- weight transposes f32 [R][Cd] -> bf16 [Cd][R] ----
    int idx = bid - 2048;
    float (*tile)[33] = (float(*)[33])smem;
    const float* src; short* dst; int R, Cd, gx, local;
    if (idx < 768)       { src = Wq; dst = WQT; R = CC;  Cd = NQK; gx = 16; local = idx; }
    else if (idx < 1536) { src = Wk; dst = WKT; R = CC;  Cd = NQK; gx = 16; local = idx - 768; }
    else if (idx < 3840) { src = Wv; dst = WVT; R = CC;  Cd = NVD; gx = 48; local = idx - 1536; }
    else                 { src = Wo; dst = WOT; R = NVD; Cd = CC;  gx = 48; local = idx - 3840; }
    int c0 = (local % gx) * 32, r0 = (local / gx) * 32;
    int tx = tid & 31, ty = tid >> 5;   // (32,8) mapping, x fastest
    #pragma unroll
    for (int i = 0; i < 4; i++)
      tile[ty + i * 8][tx] = src[(size_t)(r0 + ty + i * 8) * Cd + c0 + tx];
    __syncthreads();
    #pragma unroll
    for (int i = 0; i < 4; i++)
      dst[(size_t)(c0 + ty + i * 8) * R + r0 + tx] = f2bf(tile[tx][ty + i * 8]);
  } else {
    // ---- RB: row 0 zeros, row j+1 = basis[j] @ WR ----
    int jp = bid - 8192;
    float* feats = smem;
    if (jp == 0) {
      if (tid < KDIM) RB[tid] = 0;
      return;
    }
    int j = jp - 1;
    int pos = j - (LL - 1);
    int api = pos < 0 ? -pos : pos;
    double ap = (double)api;
    float sgn = pos > 0 ? 1.0f : (pos < 0 ? -1.0f : 0.0f);
    if (tid < FSZ) {
      double xhl = 3.0 + 7.0 * (double)tid / 31.0;
      double hl = exp2(xhl);
      float fe = (float)exp2(-ap / hl);
      feats[tid] = fe; feats[FSZ + tid] = sgn * fe;
    } else if (tid < 2 * FSZ) {
      int i = tid - FSZ;
      double cw = exp2((double)(i + 1)) - 1.0;
      float fc = cw > ap ? 1.0f : 0.0f;
      feats[2 * FSZ + i] = fc; feats[3 * FSZ + i] = sgn * fc;
    } else if (tid < 3 * FSZ) {
      int i = tid - 2 * FSZ;
      double mean = 32.0 + 32.0 * (double)i;
      double conc = (mean * (1.0 / 16.0)) * (mean * (1.0 / 16.0));
      double rate = mean * (1.0 / 256.0);
      double lp = (conc - 1.0) * log(ap) - rate * ap - lgamma(conc) + conc * log(rate);
      double pdf = exp(lp) + 1e-8;
      float fg = (float)(pdf / (double)pmax);
      feats[4 * FSZ + i] = fg; feats[5 * FSZ + i] = sgn * fg;
    }
    __syncthreads();
    if (tid < KDIM) {
      float acc = 0.f;
      #pragma unroll 4
      for (int f = 0; f < NFEAT; f++) acc += feats[f] * WR[f * KDIM + tid];
      RB[jp * KDIM + tid] = f2bf(acc);
    }
  }
}

// ---------------- 128x128 GEMM, BK=32, 3-buffer ring, counted vmcnt ----------------
// (R14/R16-validated configuration: the measured local optimum.)
// MODE 0: fused QKV (QP only + LDS-transposed coalesced VT). MODE 1: f32 out.
template<int MODE>
__global__ __launch_bounds__(256, 3)
void k_gemm3(const short* __restrict__ A, const short* __restrict__ Bt,
             int Ndim, int Kdim,
             const float* __restrict__ c0, const float* __restrict__ c1,
             const float* __restrict__ c2, const float* __restrict__ c3,
             void* __restrict__ D0, void* __restrict__ D1,
             void* __restrict__ D2, void* __restrict__ D3) {
  __shared__ short sAB[2][3][128][32];   // [0]=A ring, [1]=B ring (48KB)

  int bid = blockIdx.x;
  int xcd = bid & 7;
  int s = bid >> 3;
  int mt = xcd * 8 + (s & 7);
  int nt = s >> 3;
  int m0 = mt * 128, n0 = nt * 128;
  int tid = threadIdx.x;
  int w = tid >> 6, l = tid & 63;
  int hi = l >> 4, lc = l & 15;
  int wr = (w >> 1) * 64, wc = (w & 1) * 64;

  int rowoff = l >> 2;
  int schunk = ((l & 3) ^ ((l >> 3) & 3)) * 8;
  const short* gA = A + (size_t)(m0 + rowoff) * Kdim + schunk;
  const short* gB = Bt + (size_t)(n0 + rowoff) * Kdim + schunk;

  f32x4 acc[4][4] = {};
  int T = Kdim >> 5;

  auto stage = [&](int d, int kt) {
    #pragma unroll
    for (int j = 0; j < 2; j++) {
      int rb = j * 64 + w * 16;
      gload_lds16(gA + (size_t)rb * Kdim + kt * 32, &sAB[0][d][rb][0]);
      gload_lds16(gB + (size_t)rb * Kdim + kt * 32, &sAB[1][d][rb][0]);
    }
  };

  stage(0, 0);
  stage(1, 1);
  asm volatile("s_waitcnt vmcnt(4)" ::: "memory");
  __builtin_amdgcn_s_barrier();
  __builtin_amdgcn_sched_barrier(0);

  int rswz = (lc >> 1) & 3;
  for (int t = 0; t < T; ++t) {
    int buf = t % 3;
    bool more = (t + 2) < T;
    if (more) stage((t + 2) % 3, t + 2);

    bf16x8 af[4], bfr[4];
    #pragma unroll
    for (int ni = 0; ni < 4; ni++)
      bfr[ni] = *(const bf16x8*)&sAB[1][buf][wc + ni * 16 + lc][(hi ^ rswz) * 8];
    #pragma unroll
    for (int mi = 0; mi < 4; mi++)
      af[mi] = *(const bf16x8*)&sAB[0][buf][wr + mi * 16 + lc][(hi ^ rswz) * 8];
    __builtin_amdgcn_s_setprio(1);
    #pragma unroll
    for (int mi = 0; mi < 4; mi++)
      #pragma unroll
      for (int ni = 0; ni < 4; ni++)
        acc[mi][ni] = __builtin_amdgcn_mfma_f32_16x16x32_bf16(af[mi], bfr[ni], acc[mi][ni], 0, 0, 0);
    __builtin_amdgcn_s_setprio(0);

    if (more) asm volatile("s_waitcnt vmcnt(4)" ::: "memory");
    else      asm volatile("s_waitcnt vmcnt(0)" ::: "memory");
    __builtin_amdgcn_s_barrier();
    __builtin_amdgcn_sched_barrier(0);
  }
  // after the final barrier all waves' LDS fragment reads are complete.

  if (MODE == 0) {
    if (n0 < NQK) {
      #pragma unroll
      for (int ni = 0; ni < 4; ni++) {
        int col = n0 + wc + ni * 16 + lc;
        float bb = c0[col] + c3[col];
        #pragma unroll
        for (int mi = 0; mi < 4; mi++)
          #pragma unroll
          for (int rr = 0; rr < 4; rr++) {
            int row = m0 + wr + mi * 16 + hi * 4 + rr;
            ((short*)D0)[(size_t)row * NQK + col] = f2bf((acc[mi][ni][rr] + bb) * SCL);
          }
      }
    } else if (n0 < 2 * NQK) {
      #pragma unroll
      for (int ni = 0; ni < 4; ni++) {
        int c = n0 - NQK + wc + ni * 16 + lc;
        float bb = c1[c];
        #pragma unroll
        for (int mi = 0; mi < 4; mi++)
          #pragma unroll
          for (int rr = 0; rr < 4; rr++) {
            int row = m0 + wr + mi * 16 + hi * 4 + rr;
            ((short*)D2)[(size_t)row * NQK + c] = f2bf(acc[mi][ni][rr] + bb);
          }
      }
    } else {
      // V region: LDS transpose -> coalesced VT[bh][v][s] stores
      int c_base = n0 - 2 * NQK;
      short* scr = &sAB[0][0][0][0] + w * (64 * 68);   // wave-private 64x68
      float bbv[4];
      #pragma unroll
      for (int ni = 0; ni < 4; ni++) bbv[ni] = c2[c_base + wc + ni * 16 + lc];
      #pragma unroll
      for (int ni = 0; ni < 4; ni++)
        #pragma unroll
        for (int mi = 0; mi < 4; mi++)
          #pragma unroll
          for (int rr = 0; rr < 4; rr++)
            scr[(mi * 16 + hi * 4 + rr) * 68 + ni * 16 + lc] =
                f2bf(acc[mi][ni][rr] + bbv[ni]);
      int bI = m0 >> 10;
      int sgbase = (m0 & (LL - 1)) + wr;
      #pragma unroll
      for (int j = 0; j < 8; j++) {
        int col_l = j * 8 + (l >> 3);
        int s_l = (l & 7) * 8;
        int c = c_base + wc + col_l;
        int hh = c / VDIM, vv = c - hh * VDIM;
        bf16x8 v8;
        #pragma unroll
        for (int e = 0; e < 8; e++) v8[e] = scr[(s_l + e) * 68 + col_l];
        short* dst = (short*)D3 + ((size_t)(bI * 8 + hh) * VDIM + vv) * LL + sgbase + s_l;
        *(bf16x8*)dst = v8;
      }
    }
  } else {
    #pragma unroll
    for (int ni = 0; ni < 4; ni++) {
      int col = n0 + wc + ni * 16 + lc;
      float bb = c0[col];
      #pragma unroll
      for (int mi = 0; mi < 4; mi++)
        #pragma unroll
        for (int rr = 0; rr < 4; rr++) {
          int row = m0 + wr + mi * 16 + hi * 4 + rr;
          ((float*)D0)[(size_t)row * Ndim + col] = acc[mi][ni][rr] + bb;
        }
    }
  }
}

// ---------------- flash attention: 128q/block, gload_lds dbuf, 1 barrier/tile ----------------
// (R14/R16-validated; unchanged)
__global__ __launch_bounds__(256, 2)
void k_attn(const short* __restrict__ Qp, const float* __restrict__ uu,
            const short* __restrict__ Kb, const short* __restrict__ Vt,
            const short* __restrict__ Rb, short* __restrict__ AO) {
  __shared__ short sK[2][64][64];
  __shared__ short sV[2][192][64];
  __shared__ short sP[128][64];

  int bid = blockIdx.x;
  int swz = (bid & 7) * 64 + (bid >> 3);   // XCD-contiguous bh
  int qt = swz & 7, bh = swz >> 3;
  int b = bh >> 3, h = bh & 7;
  int q0 = qt * 128;
  int tid = threadIdx.x;
  int w = tid >> 6, l = tid & 63;
  int hi = l >> 4, lc = l & 15;

  int base = (w & 1) * 64;
  int par = w >> 1;
  int rbase = par ? 0 : 1024;

  bf16x8 aq1[2][2], aq2[2][2];
  {
    float u8[2][8];
    #pragma unroll
    for (int kk = 0; kk < 2; kk++)
      #pragma unroll
      for (int j = 0; j < 8; j++)
        u8[kk][j] = uu[h * KDIM + kk * 32 + hi * 8 + j] * SCL;
    #pragma unroll
    for (int mi = 0; mi < 2; mi++) {
      int qglob = q0 + base + par + 2 * (mi * 16 + lc);
      const short* qpg = Qp + (size_t)(b * LL + qglob) * NQK + h * KDIM;
      aq1[mi][0] = *(const bf16x8*)&qpg[hi * 8];
      aq1[mi][1] = *(const bf16x8*)&qpg[32 + hi * 8];
      int qsrow = q0 / 2 + base / 2 + par + mi * 16 + lc;
      const short* qsg = Qp + (size_t)(b * LL + qsrow) * NQK + h * KDIM;
      #pragma unroll
      for (int kk = 0; kk < 2; kk++) {
        bf16x8 t = *(const bf16x8*)&qsg[kk * 32 + hi * 8];
        #pragma unroll
        for (int j = 0; j < 8; j++)
          aq2[mi][kk][j] = f2bf(bf2f(t[j]) - u8[kk][j]);
      }
    }
  }

  const short* kg = Kb + (size_t)(b * LL) * NQK + h * KDIM;
  const short* vg = Vt + (size_t)bh * VDIM * LL;
  const short* rg = Rb + (size_t)rbase * KDIM;

  int srow = l >> 3;
  int schunk = ((l & 7) ^ srow) * 8;

  float mrun[2][4], lrun[2][4];
  #pragma unroll
  for (int mi = 0; mi < 2; mi++)
    #pragma unroll
    for (int r = 0; r < 4; r++) { mrun[mi][r] = -INFINITY; lrun[mi][r] = 0.f; }
  f32x4 oacc[2][12] = {};

  #pragma unroll
  for (int j = 0; j < 2; j++) {
    int rb2 = (j * 4 + w) * 8;
    gload_lds16(kg + (size_t)(rb2 + srow) * NQK + schunk, &sK[0][rb2][0]);
  }
  #pragma unroll
  for (int j = 0; j < 6; j++) {
    int rb2 = (j * 4 + w) * 8;
    gload_lds16(vg + (size_t)(rb2 + srow) * LL + schunk, &sV[0][rb2][0]);
  }
  __syncthreads();

  int swzk = (lc & 7) << 3;

  for (int t = 0; t < 16; t++) {
    int k0 = t * 64;
    int bf = t & 1;

    // RB frags first (minimal wait in the per-wave vmcnt queue)
    bf16x8 br[2][4];
    #pragma unroll
    for (int kk = 0; kk < 2; kk++)
      #pragma unroll
      for (int ni = 0; ni < 4; ni++)
        br[kk][ni] = *(const bf16x8*)&rg[(size_t)(k0 + ni * 16 + lc) * KDIM + kk * 32 + hi * 8];

    if (t < 15) {
      int kn = k0 + 64;
      #pragma unroll
      for (int j = 0; j < 2; j++) {
        int rb2 = (j * 4 + w) * 8;
        gload_lds16(kg + (size_t)(kn + rb2 + srow) * NQK + schunk, &sK[bf ^ 1][rb2][0]);
      }
      #pragma unroll
      for (int j = 0; j < 6; j++) {
        int rb2 = (j * 4 + w) * 8;
        gload_lds16(vg + (size_t)(rb2 + srow) * LL + kn + schunk, &sV[bf ^ 1][rb2][0]);
      }
    }

    f32x4 s[2][4] = {};
    #pragma unroll
    for (int kk = 0; kk < 2; kk++) {
      #pragma unroll
      for (int ni = 0; ni < 4; ni++) {
        bf16x8 bk = *(const bf16x8*)&sK[bf][ni * 16 + lc][(kk * 32 + hi * 8) ^ swzk];
        #pragma unroll
        for (int mi = 0; mi < 2; mi++) {
          s[mi][ni] = __builtin_amdgcn_mfma_f32_16x16x32_bf16(aq1[mi][kk], bk, s[mi][ni], 0, 0, 0);
          s[mi][ni] = __builtin_amdgcn_mfma_f32_16x16x32_bf16(aq2[mi][kk], br[kk][ni], s[mi][ni], 0, 0, 0);
        }
      }
    }

    float lmx[2][4];
    float dmax = -INFINITY;
    #pragma unroll
    for (int mi = 0; mi < 2; mi++) {
      #pragma unroll
      for (int r = 0; r < 4; r++) {
        float m3 = fmaxf(fmaxf(s[mi][0][r], s[mi][1][r]), fmaxf(s[mi][2][r], s[mi][3][r]));
        lmx[mi][r] = m3;
        dmax = fmaxf(dmax, m3 - mrun[mi][r]);
      }
    }

    if (__any(dmax > 8.0f)) {
      #pragma unroll
      for (int mi = 0; mi < 2; mi++) {
        #pragma unroll
        for (int r = 0; r < 4; r++) {
          float m3 = lmx[mi][r];
          m3 = fmaxf(m3, __shfl_xor(m3, 1, 64));
          m3 = fmaxf(m3, __shfl_xor(m3, 2, 64));
          m3 = fmaxf(m3, __shfl_xor(m3, 4, 64));
          m3 = fmaxf(m3, __shfl_xor(m3, 8, 64));
          float mnew = fmaxf(mrun[mi][r], m3);
          float fc = __expf(mrun[mi][r] - mnew);
          mrun[mi][r] = mnew;
          lrun[mi][r] *= fc;
          #pragma unroll
          for (int ni = 0; ni < 12; ni++)
            oacc[mi][ni][r] *= fc;
        }
      }
    }

    #pragma unroll
    for (int mi = 0; mi < 2; mi++) {
      #pragma unroll
      for (int r = 0; r < 4; r++) {
        int prow = w * 32 + mi * 16 + 4 * hi + r;
        int pxor = ((4 * hi + r) & 7) << 3;
        float ps = 0.f;
        #pragma unroll
        for (int ni = 0; ni < 4; ni++) {
          float p = __expf(s[mi][ni][r] - mrun[mi][r]);
          ps += p;
          sP[prow][(ni * 16 + lc) ^ pxor] = f2bf(p);
        }
        lrun[mi][r] += ps;
      }
    }

    __builtin_amdgcn_s_setprio(1);
    #pragma unroll
    for (int kk = 0; kk < 2; kk++) {
      bf16x8 pa[2];
      #pragma unroll
      for (int mi = 0; mi < 2; mi++)
        pa[mi] = *(const bf16x8*)&sP[w * 32 + mi * 16 + lc][(kk * 32 + hi * 8) ^ swzk];
      #pragma unroll
      for (int ni = 0; ni < 12; ni++) {
        bf16x8 bv = *(const bf16x8*)&sV[bf][ni * 16 + lc][(kk * 32 + hi * 8) ^ swzk];
        #pragma unroll
        for (int mi = 0; mi < 2; mi++)
          oacc[mi][ni] = __builtin_amdgcn_mfma_f32_16x16x32_bf16(pa[mi], bv, oacc[mi][ni], 0, 0, 0);
      }
    }
    __builtin_amdgcn_s_setprio(0);

    __syncthreads();
  }

  // epilogue: reduce the deferred l partials (once), normalize, store
  #pragma unroll
  for (int mi = 0; mi < 2; mi++) {
    #pragma unroll
    for (int r = 0; r < 4; r++) {
      float L = lrun[mi][r];
      L += __shfl_xor(L, 1, 64);
      L += __shfl_xor(L, 2, 64);
      L += __shfl_xor(L, 4, 64);
      L += __shfl_xor(L, 8, 64);
      float iv = 1.0f / L;
      int qglob = q0 + base + par + 2 * (mi * 16 + 4 * hi + r);
      short* ao = AO + (size_t)(b * LL + qglob) * NVD + h * VDIM;
      #pragma unroll
      for (int ni = 0; ni < 12; ni++)
        ao[ni * 16 + lc] = f2bf(oacc[mi][ni][r] * iv);
    }
  }
}

}  // namespace

extern "C" void kernel_launch(void* const* d_in, const int* in_sizes, int n_in,
                              void* d_out, int out_size, void* d_ws, size_t ws_size,
                              hipStream_t stream) {
  (void)in_sizes; (void)n_in; (void)out_size; (void)ws_size;
  const float* x  = (const float*)d_in[0];
  const float* Wq = (const float*)d_in[1];
  const float* bq = (const float*)d_in[2];
  const float* Wk = (const float*)d_in[3];
  const float* bk = (const float*)d_in[4];
  const float* Wv = (const float*)d_in[5];
  const float* bv = (const float*)d_in[6];
  const float* Wo = (const float*)d_in[7];
  const float* bo = (const float*)d_in[8];
  const float* WR = (const float*)d_in[9];
  const float* uu = (const float*)d_in[10];
  // d_in[11] (v) intentionally unused: term4 is constant along the softmax axis.

  // Host-side gamma-pdf max (input-independent; unimodal -> mode neighborhood).
  double pmaxd = 0.0;
  for (int i = 0; i < 32; i++) {
    double mean = 32.0 + 32.0 * (double)i;
    double conc = (mean / 16.0) * (mean / 16.0);
    double rate = mean / 256.0;
    double mode = (conc - 1.0) / rate;
    long m0i = (long)floor(mode);
    for (long dj = -2; dj <= 2; dj++) {
      long ap = m0i + dj;
      if (ap < 1) ap = 1;
      if (ap > 1023) ap = 1023;
      double lp = (conc - 1.0) * log((double)ap) - rate * (double)ap
                  - lgamma(conc) + conc * log(rate);
      double pdf = exp(lp) + 1e-8;
      if (pdf > pmaxd) pmaxd = pdf;
    }
  }
  float pmax = (float)pmaxd;

  char* ws = (char*)d_ws;
  size_t off = 0;
  auto alloc = [&](size_t bytes) -> void* {
    void* p = ws + off;
    off += (bytes + 255) & ~(size_t)255;
    return p;
  };
  short* RB      = (short*)alloc((size_t)2048 * 64 * 2);
  short* XB      = (short*)alloc((size_t)MR * CC * 2);
  short* WALL    = (short*)alloc((size_t)NQKV * CC * 2);   // [WQT;WKT;WVT]
  short* WOT     = (short*)alloc((size_t)CC * NVD * 2);
  short* QP      = (short*)alloc((size_t)MR * NQK * 2);
  short* KB      = (short*)alloc((size_t)MR * NQK * 2);
  short* VT      = (short*)alloc((size_t)MR * NVD * 2);
  short* AO      = (short*)alloc((size_t)MR * NVD * 2);

  short* WQT = WALL;
  short* WKT = WALL + (size_t)NQK * CC;
  short* WVT = WALL + (size_t)(2 * NQK) * CC;

  // fused preprocessing: conversion + transposes + RB in one dispatch
  k_prep<<<10240, 256, 0, stream>>>(x, XB, Wq, WQT, Wk, WKT, Wv, WVT, Wo, WOT,
                                    WR, pmax, RB);
  // fused Q/K/V projections (QP only + V transposed via LDS): 64 x 20 = 1280 blocks
  k_gemm3<0><<<dim3(MR / 128 * (NQKV / 128)), 256, 0, stream>>>(
      XB, WALL, NQKV, CC, bq, bk, bv, uu, QP, nullptr, KB, VT);
  k_attn<<<dim3(LL / 128 * BB * HH), 256, 0, stream>>>(QP, uu, KB, VT, RB, AO);
  // output projection: 64 x 12 = 768 blocks
  k_gemm3<1><<<dim3(MR / 128 * (CC / 128)), 256, 0, stream>>>(
      AO, WOT, CC, NVD, bo, nullptr, nullptr, nullptr, d_out, nullptr, nullptr, nullptr);
}